// Round 2
// baseline (448.403 us; speedup 1.0000x reference)
//
#include <hip/hip_runtime.h>
#include <hip/hip_bf16.h>

#define N_NODES 20000
#define N_EDGES 320000

typedef __attribute__((ext_vector_type(8))) short short8;
typedef __attribute__((ext_vector_type(4))) float f32x4;

static __device__ __forceinline__ unsigned short f2bf(float f) {
  __hip_bfloat16 h = __float2bfloat16(f);
  union { __hip_bfloat16 h; unsigned short u; } cv; cv.h = h; return cv.u;
}

static __device__ __forceinline__ unsigned int pk2(float a, float b) {
  return (unsigned int)f2bf(a) | ((unsigned int)f2bf(b) << 16);
}

static __device__ __forceinline__ float gelu_exact(float v) {
  return 0.5f * v * (1.0f + erff(v * 0.70710678118654752f));
}

// XOR swizzle: spread rows across 16B LDS granules (G4 fix for stride-512B/1024B tiles)
#define SWZ(row, byteoff) ((byteoff) ^ (((row) & 7) << 4))
// swizzle for fp32 U tile keyed off address bits (col-segment + row parity)
#define SWZU(b) ((b) ^ ((((b) >> 8) & 7) << 4))

// ---------------------------------------------------------------- zero
__global__ void zero_kernel(float4* __restrict__ S4, float4* __restrict__ deg4) {
  int idx = blockIdx.x * blockDim.x + threadIdx.x;
  S4[idx] = make_float4(0.f, 0.f, 0.f, 0.f);
  if (idx < N_NODES / 4) deg4[idx] = make_float4(0.f, 0.f, 0.f, 0.f);
}

// ---------------------------------------------------------------- weight pack
// Pack W[K][Nc] (row-major f32) into bf16 MFMA-B-fragment order:
// P[(cf*(K/32)+t)*512 + l*8 + i] = W[t*32 + (l>>4)*8 + i][cf*16 + (l&15)]
__global__ void pack_kernel(const float* __restrict__ W1m, const float* __restrict__ W2m,
                            const float* __restrict__ W1u, const float* __restrict__ W2u,
                            unsigned short* __restrict__ P1m, unsigned short* __restrict__ P2m,
                            unsigned short* __restrict__ P1u, unsigned short* __restrict__ P2u) {
  int idx = blockIdx.x * blockDim.x + threadIdx.x;
  const float* W; unsigned short* P; int K, Nc, local;
  if (idx < 65536)        { W = W1m; P = P1m; K = 256; Nc = 256; local = idx; }
  else if (idx < 131072)  { W = W2m; P = P2m; K = 256; Nc = 256; local = idx - 65536; }
  else if (idx < 262144)  { W = W1u; P = P1u; K = 256; Nc = 512; local = idx - 131072; }
  else                    { W = W2u; P = P2u; K = 512; Nc = 256; local = idx - 262144; }
  int frag = local >> 9, wi = local & 511;
  int l = wi >> 3, i = wi & 7;
  int kf = K >> 5;
  int cf = frag / kf, t = frag % kf;
  int k = t * 32 + (l >> 4) * 8 + i;
  int n = cf * 16 + (l & 15);
  P[local] = f2bf(W[(size_t)k * Nc + n]);
}

// ---------------------------------------------------------------- edge kernel
// 64 edges/block, 4 waves. h = node[src]+edge_emb -> LDS bf16 (swizzled);
// h1 = gelu(h @ W1m + b1m) via MFMA; atomic scatter h1 into S[dst], deg[dst]+=1.
__global__ __launch_bounds__(256) void edge_kernel(
    const float* __restrict__ node, const float* __restrict__ eemb,
    const int* __restrict__ src, const int* __restrict__ dst,
    const unsigned short* __restrict__ P1m, const float* __restrict__ b1m,
    float* __restrict__ S, float* __restrict__ deg) {
  __shared__ unsigned short tA[64 * 256];
  __shared__ int dstS[64];
  const int tid = threadIdx.x;
  const int e0 = blockIdx.x * 64;
  {
    const int r = tid >> 2;
    const int cs = (tid & 3) * 64;
    const int e = e0 + r;
    const int se = src[e];
    if ((tid & 3) == 0) dstS[r] = dst[e];
    const float4* ep = (const float4*)(eemb + (size_t)e * 256 + cs);
    const float4* np = (const float4*)(node + (size_t)se * 256 + cs);
#pragma unroll
    for (int i = 0; i < 8; ++i) {
      float4 a = ep[2 * i],     b = np[2 * i];
      float4 c = ep[2 * i + 1], d = np[2 * i + 1];
      uint4 p;
      p.x = pk2(a.x + b.x, a.y + b.y);
      p.y = pk2(a.z + b.z, a.w + b.w);
      p.z = pk2(c.x + d.x, c.y + d.y);
      p.w = pk2(c.z + d.z, c.w + d.w);
      *(uint4*)((char*)tA + SWZ(r, r * 512 + (cs + i * 8) * 2)) = p;
    }
  }
  __syncthreads();
  if (tid < 64) atomicAdd(&deg[dstS[tid]], 1.0f);

  const int w = tid >> 6, l = tid & 63;
  const int lr = l & 15, lh = l >> 4;
  f32x4 acc[4][4];
#pragma unroll
  for (int c = 0; c < 4; ++c) {
    float bb = b1m[w * 64 + c * 16 + lr];
#pragma unroll
    for (int r4 = 0; r4 < 4; ++r4) acc[r4][c] = f32x4{bb, bb, bb, bb};
  }
#pragma unroll
  for (int t = 0; t < 8; ++t) {
    short8 af[4], bfr[4];
#pragma unroll
    for (int r4 = 0; r4 < 4; ++r4) {
      int row = r4 * 16 + lr;
      af[r4] = *(const short8*)((const char*)tA + SWZ(row, row * 512 + t * 64 + lh * 16));
    }
#pragma unroll
    for (int c = 0; c < 4; ++c)
      bfr[c] = *(const short8*)(P1m + (size_t)(((w * 4 + c) * 8 + t) * 512 + l * 8));
#pragma unroll
    for (int r4 = 0; r4 < 4; ++r4)
#pragma unroll
      for (int c = 0; c < 4; ++c)
        acc[r4][c] = __builtin_amdgcn_mfma_f32_16x16x32_bf16(af[r4], bfr[c], acc[r4][c], 0, 0, 0);
  }
#pragma unroll
  for (int r4 = 0; r4 < 4; ++r4) {
#pragma unroll
    for (int j = 0; j < 4; ++j) {
      int row = r4 * 16 + lh * 4 + j;
      float* Sp = S + (size_t)dstS[row] * 256;
#pragma unroll
      for (int c = 0; c < 4; ++c) {
        int col = w * 64 + c * 16 + lr;
        atomicAdd(Sp + col, gelu_exact(acc[r4][c][j]));
      }
    }
  }
}

// ---------------------------------------------------------------- node kernel
// 64 nodes/block: A2 = S/max(deg,1); agg = A2@W2m + (deg>0)b2m;
// H = gelu(agg@W1u + b1u); U = H@W2u + b2u; out = LN(node + U)*gamma + beta.
__global__ __launch_bounds__(256) void node_kernel(
    const float* __restrict__ node, const float* __restrict__ S, const float* __restrict__ deg,
    const unsigned short* __restrict__ P2m, const float* __restrict__ b2m,
    const unsigned short* __restrict__ P1u, const float* __restrict__ b1u,
    const unsigned short* __restrict__ P2u, const float* __restrict__ b2u,
    const float* __restrict__ gamma, const float* __restrict__ beta,
    float* __restrict__ out) {
  __shared__ unsigned short tAB[2][64 * 256];  // 64 KB: [0]=A2, [1]=agg; reused as fp32 U
  __shared__ unsigned short tH[64 * 512];      // 64 KB
  __shared__ float fmu[64], frs[64], fflag[64];
  float* tU = (float*)tAB;
  const int tid = threadIdx.x;
  const int n0 = blockIdx.x * 64;
  const int r = tid >> 2;
  const int cs = (tid & 3) * 64;
  const int n = n0 + r;
  const bool valid = n < N_NODES;
  {
    float dg = valid ? deg[n] : 0.0f;
    float rec = 1.0f / fmaxf(dg, 1.0f);
    if ((tid & 3) == 0) fflag[r] = (dg > 0.0f) ? 1.0f : 0.0f;
    const float4* sp = (const float4*)(S + (size_t)n * 256 + cs);
#pragma unroll
    for (int i = 0; i < 8; ++i) {
      float4 a = valid ? sp[2 * i]     : make_float4(0.f, 0.f, 0.f, 0.f);
      float4 b = valid ? sp[2 * i + 1] : make_float4(0.f, 0.f, 0.f, 0.f);
      uint4 p;
      p.x = pk2(a.x * rec, a.y * rec);
      p.y = pk2(a.z * rec, a.w * rec);
      p.z = pk2(b.x * rec, b.y * rec);
      p.w = pk2(b.z * rec, b.w * rec);
      *(uint4*)((char*)tAB[0] + SWZ(r, r * 512 + (cs + i * 8) * 2)) = p;
    }
  }
  __syncthreads();
  const int w = tid >> 6, l = tid & 63, lr = l & 15, lh = l >> 4;

  // ---- GEMM1: agg = A2 @ W2m + flag*b2m -> tAB[1] (bf16)
  {
    f32x4 acc[4][4];
#pragma unroll
    for (int r4 = 0; r4 < 4; ++r4)
#pragma unroll
      for (int c = 0; c < 4; ++c) acc[r4][c] = f32x4{0.f, 0.f, 0.f, 0.f};
#pragma unroll
    for (int t = 0; t < 8; ++t) {
      short8 af[4], bfr[4];
#pragma unroll
      for (int r4 = 0; r4 < 4; ++r4) {
        int row = r4 * 16 + lr;
        af[r4] = *(const short8*)((const char*)tAB[0] + SWZ(row, row * 512 + t * 64 + lh * 16));
      }
#pragma unroll
      for (int c = 0; c < 4; ++c)
        bfr[c] = *(const short8*)(P2m + (size_t)(((w * 4 + c) * 8 + t) * 512 + l * 8));
#pragma unroll
      for (int r4 = 0; r4 < 4; ++r4)
#pragma unroll
        for (int c = 0; c < 4; ++c)
          acc[r4][c] = __builtin_amdgcn_mfma_f32_16x16x32_bf16(af[r4], bfr[c], acc[r4][c], 0, 0, 0);
    }
#pragma unroll
    for (int r4 = 0; r4 < 4; ++r4)
#pragma unroll
      for (int c = 0; c < 4; ++c) {
        int col = w * 64 + c * 16 + lr;
        float bm = b2m[col];
#pragma unroll
        for (int j = 0; j < 4; ++j) {
          int row = r4 * 16 + lh * 4 + j;
          float v = acc[r4][c][j] + fflag[row] * bm;
          *(unsigned short*)((char*)tAB[1] + SWZ(row, row * 512 + col * 2)) = f2bf(v);
        }
      }
  }
  __syncthreads();

  // ---- GEMM2: H = gelu(agg @ W1u + b1u) -> tH (64x512 bf16)
  {
    f32x4 acc[4][8];
#pragma unroll
    for (int r4 = 0; r4 < 4; ++r4)
#pragma unroll
      for (int c = 0; c < 8; ++c) acc[r4][c] = f32x4{0.f, 0.f, 0.f, 0.f};
#pragma unroll
    for (int t = 0; t < 8; ++t) {
      short8 af[4], bfr[8];
#pragma unroll
      for (int r4 = 0; r4 < 4; ++r4) {
        int row = r4 * 16 + lr;
        af[r4] = *(const short8*)((const char*)tAB[1] + SWZ(row, row * 512 + t * 64 + lh * 16));
      }
#pragma unroll
      for (int c = 0; c < 8; ++c)
        bfr[c] = *(const short8*)(P1u + (size_t)(((w * 8 + c) * 8 + t) * 512 + l * 8));
#pragma unroll
      for (int r4 = 0; r4 < 4; ++r4)
#pragma unroll
        for (int c = 0; c < 8; ++c)
          acc[r4][c] = __builtin_amdgcn_mfma_f32_16x16x32_bf16(af[r4], bfr[c], acc[r4][c], 0, 0, 0);
    }
#pragma unroll
    for (int r4 = 0; r4 < 4; ++r4)
#pragma unroll
      for (int c = 0; c < 8; ++c) {
        int col = w * 128 + c * 16 + lr;
        float b1 = b1u[col];
#pragma unroll
        for (int j = 0; j < 4; ++j) {
          int row = r4 * 16 + lh * 4 + j;
          float v = gelu_exact(acc[r4][c][j] + b1);
          *(unsigned short*)((char*)tH + SWZ(row, row * 1024 + col * 2)) = f2bf(v);
        }
      }
  }
  __syncthreads();

  // ---- GEMM3: U = H @ W2u + b2u -> tU (fp32, SWZU)  [tAB dead -> reuse as tU]
  {
    f32x4 acc[4][4];
#pragma unroll
    for (int r4 = 0; r4 < 4; ++r4)
#pragma unroll
      for (int c = 0; c < 4; ++c) acc[r4][c] = f32x4{0.f, 0.f, 0.f, 0.f};
#pragma unroll
    for (int t = 0; t < 16; ++t) {
      short8 af[4], bfr[4];
#pragma unroll
      for (int r4 = 0; r4 < 4; ++r4) {
        int row = r4 * 16 + lr;
        af[r4] = *(const short8*)((const char*)tH + SWZ(row, row * 1024 + t * 64 + lh * 16));
      }
#pragma unroll
      for (int c = 0; c < 4; ++c)
        bfr[c] = *(const short8*)(P2u + (size_t)(((w * 4 + c) * 16 + t) * 512 + l * 8));
#pragma unroll
      for (int r4 = 0; r4 < 4; ++r4)
#pragma unroll
        for (int c = 0; c < 4; ++c)
          acc[r4][c] = __builtin_amdgcn_mfma_f32_16x16x32_bf16(af[r4], bfr[c], acc[r4][c], 0, 0, 0);
    }
#pragma unroll
    for (int r4 = 0; r4 < 4; ++r4)
#pragma unroll
      for (int c = 0; c < 4; ++c) {
        int col = w * 64 + c * 16 + lr;
        float b2 = b2u[col];
#pragma unroll
        for (int j = 0; j < 4; ++j) {
          int row = r4 * 16 + lh * 4 + j;
          *(float*)((char*)tU + SWZU(row * 1024 + col * 4)) = acc[r4][c][j] + b2;
        }
      }
  }
  __syncthreads();

  // ---- residual + LayerNorm stats
  {
    float sum = 0.f, sq = 0.f;
#pragma unroll
    for (int i = 0; i < 16; ++i) {
      int byte = SWZU(r * 1024 + (cs + i * 4) * 4);
      float4 v = *(float4*)((char*)tU + byte);
      if (valid) {
        const float4 nb = *(const float4*)(node + (size_t)n * 256 + cs + i * 4);
        v.x += nb.x; v.y += nb.y; v.z += nb.z; v.w += nb.w;
        *(float4*)((char*)tU + byte) = v;
      }
      sum += v.x + v.y + v.z + v.w;
      sq += v.x * v.x + v.y * v.y + v.z * v.z + v.w * v.w;
    }
    sum += __shfl_xor(sum, 1); sum += __shfl_xor(sum, 2);
    sq  += __shfl_xor(sq, 1);  sq  += __shfl_xor(sq, 2);
    if ((tid & 3) == 0) {
      float mu = sum * (1.0f / 256.0f);
      fmu[r] = mu;
      frs[r] = rsqrtf(fmaxf(sq * (1.0f / 256.0f) - mu * mu, 0.0f) + 1e-5f);
    }
  }
  __syncthreads();
#pragma unroll
  for (int i = 0; i < 16; ++i) {
    int f4 = i * 256 + tid;
    int row = f4 >> 6;
    int c4 = f4 & 63;
    int nn = n0 + row;
    if (nn < N_NODES) {
      float4 v = *(float4*)((char*)tU + SWZU(row * 1024 + c4 * 16));
      float mu = fmu[row], rs = frs[row];
      float4 g  = *(const float4*)(gamma + c4 * 4);
      float4 bt = *(const float4*)(beta + c4 * 4);
      float4 o;
      o.x = (v.x - mu) * rs * g.x + bt.x;
      o.y = (v.y - mu) * rs * g.y + bt.y;
      o.z = (v.z - mu) * rs * g.z + bt.z;
      o.w = (v.w - mu) * rs * g.w + bt.w;
      *(float4*)(out + (size_t)nn * 256 + c4 * 4) = o;
    }
  }
}

// ---------------------------------------------------------------- launch
extern "C" void kernel_launch(void* const* d_in, const int* in_sizes, int n_in,
                              void* d_out, int out_size, void* d_ws, size_t ws_size,
                              hipStream_t stream) {
  const float* node = (const float*)d_in[0];
  const int* eidx = (const int*)d_in[1];   // harness delivers integer inputs as int32
  const float* eemb = (const float*)d_in[2];
  const float* W1m = (const float*)d_in[3];
  const float* b1m = (const float*)d_in[4];
  const float* W2m = (const float*)d_in[5];
  const float* b2m = (const float*)d_in[6];
  const float* W1u = (const float*)d_in[7];
  const float* b1u = (const float*)d_in[8];
  const float* W2u = (const float*)d_in[9];
  const float* b2u = (const float*)d_in[10];
  const float* gamma = (const float*)d_in[11];
  const float* beta = (const float*)d_in[12];
  float* out = (float*)d_out;  // doubles as the scatter accumulator S [N,256] f32

  char* ws = (char*)d_ws;
  float* deg = (float*)ws;                                   // N f32  (80000 B)
  unsigned short* P1m = (unsigned short*)(ws + 81920);       // 131072 B
  unsigned short* P2m = (unsigned short*)(ws + 212992);      // 131072 B
  unsigned short* P1u = (unsigned short*)(ws + 344064);      // 262144 B
  unsigned short* P2u = (unsigned short*)(ws + 606208);      // 262144 B
  const int* src = eidx;
  const int* dst = eidx + N_EDGES;

  zero_kernel<<<N_NODES * 64 / 256, 256, 0, stream>>>((float4*)out, (float4*)deg);
  pack_kernel<<<393216 / 256, 256, 0, stream>>>(W1m, W2m, W1u, W2u, P1m, P2m, P1u, P2u);
  edge_kernel<<<N_EDGES / 64, 256, 0, stream>>>(node, eemb, src, dst, P1m, b1m, out, deg);
  node_kernel<<<(N_NODES + 63) / 64, 256, 0, stream>>>(node, out, deg, P2m, b2m,
                                                       P1u, b1u, P2u, b2u, gamma, beta, out);
}